// Round 3
// baseline (105.209 us; speedup 1.0000x reference)
//
#include <hip/hip_runtime.h>
#include <hip/hip_bf16.h>

#define TWO_N  8192
#define N_HALF 4096
#define DIMS   256

typedef __bf16 bf16x8 __attribute__((ext_vector_type(8)));
typedef float  f32x4  __attribute__((ext_vector_type(4)));
typedef unsigned short ushort8v __attribute__((ext_vector_type(8)));

__device__ __forceinline__ float fast_exp2(float x) {
#if __has_builtin(__builtin_amdgcn_exp2f)
    return __builtin_amdgcn_exp2f(x);
#else
    float r; asm("v_exp_f32 %0, %1" : "=v"(r) : "v"(x)); return r;
#endif
}

// ---------------------------------------------------------------------------
// Kernel 1: normalize rows of reps = cat([zjs, zis]), pre-scale by
// sqrt(2*log2(e)) so the MFMA dot equals (1/TEMP)*log2(e)*sim, store in MFMA
// fragment-swizzled order: chunk = ((row/16)*8 + kk)*64 + quad*16 + (row%16);
// chunk = 8 bf16 = elements k in [quad*8 + kk*32, +8) of that row.
// One 32-lane half-wave per row (8 rows / 256-thread block).
// ---------------------------------------------------------------------------
__global__ __launch_bounds__(256) void nrm_kernel(const float* __restrict__ zis,
                                                  const float* __restrict__ zjs,
                                                  unsigned short* __restrict__ swz)
{
    const int tid = threadIdx.x;
    const int l32 = tid & 31;
    const int row = blockIdx.x * 8 + (tid >> 5);
    const int k0  = l32 * 8;

    const float* src = (row < N_HALF) ? (zjs + (size_t)row * DIMS)
                                      : (zis + (size_t)(row - N_HALF) * DIMS);
    const float4 v0 = reinterpret_cast<const float4*>(src + k0)[0];
    const float4 v1 = reinterpret_cast<const float4*>(src + k0 + 4)[0];
    float ss = v0.x * v0.x + v0.y * v0.y + v0.z * v0.z + v0.w * v0.w
             + v1.x * v1.x + v1.y * v1.y + v1.z * v1.z + v1.w * v1.w;
#pragma unroll
    for (int m = 1; m < 32; m <<= 1) ss += __shfl_xor(ss, m, 64);
    // norms ~16 for N(0,1) rows; cosine eps path can never trigger
    const float inv = rsqrtf(ss) * 1.69864360045f;  // * sqrt(2*log2(e))

    const float vals[8] = {v0.x, v0.y, v0.z, v0.w, v1.x, v1.y, v1.z, v1.w};
    ushort8v o;
#pragma unroll
    for (int j = 0; j < 8; ++j) {
        __hip_bfloat16 b = __float2bfloat16(vals[j] * inv);
        o[j] = *reinterpret_cast<unsigned short*>(&b);
    }
    const int chunk = ((row >> 4) * 8 + (l32 >> 2)) * 64 + (l32 & 3) * 16 + (row & 15);
    *reinterpret_cast<ushort8v*>(swz + (size_t)chunk * 8) = o;
}

// ---------------------------------------------------------------------------
// Kernel 2: fused scaled-Gram (bf16 MFMA) + exp2 partial row sums + diag mask
// + positive extraction.
//
// Grid 1024 x 256 (4 waves). Block tile: 128 rows x 512 cols.
//   rg = (bid>>3)&63 -> 128-row group;  cs = (bid&7)*2 + (bid>>9) -> 512-col
//   strip (XCD-swizzled: all blocks sharing cs sit on one XCD's L2).
// Wave w: rows [rg*128 + w*32, +32) x all 512 cols. B frags (2 groups of 16
// rows, full K) hoisted into 64 VGPRs; A tile (16 cols) single-buffered,
// 4 waves/SIMD hide the L2 latency (launch_bounds(256,4), VGPR <= 128).
// ---------------------------------------------------------------------------
__global__ __launch_bounds__(256, 4) void ntx_kernel(const __bf16* __restrict__ swz,
                                                     float* __restrict__ rowsum_part,
                                                     float* __restrict__ pos_part)
{
    const int lane = threadIdx.x & 63;
    const int wave = threadIdx.x >> 6;
    const int l15  = lane & 15;
    const int quad = lane >> 4;

    const int rg     = (blockIdx.x >> 3) & 63;
    const int cs     = (blockIdx.x & 7) * 2 + (blockIdx.x >> 9);
    const int wr0    = rg * 128 + wave * 32;
    const int c_base = cs * 512;
    const int p0     = wr0 ^ N_HALF;     // partner (positive) col block

    // Hoist B (row) fragments: 2 groups of 16 rows, 8 K-chunks each = 64 VGPR.
    bf16x8 bfrag[2][8];
#pragma unroll
    for (int t = 0; t < 2; ++t) {
        const __bf16* bp = swz + (size_t)((wr0 >> 4) + t) * 4096 + lane * 8;
#pragma unroll
        for (int kk = 0; kk < 8; ++kk)
            bfrag[t][kk] = *reinterpret_cast<const bf16x8*>(bp + kk * 512);
    }

    float sum_exp[2] = {0.f, 0.f};
    float pos_acc = 0.f;

#pragma unroll 1
    for (int it = 0; it < 32; ++it) {
        // A tile: 16 cols x K=256, uniform base + lane*16B + kk imm -> coalesced.
        const __bf16* ap = swz + (size_t)(cs * 32 + it) * 4096 + lane * 8;
        bf16x8 a[8];
#pragma unroll
        for (int kk = 0; kk < 8; ++kk)
            a[kk] = *reinterpret_cast<const bf16x8*>(ap + kk * 512);

        f32x4 acc[2] = {{0.f, 0.f, 0.f, 0.f}, {0.f, 0.f, 0.f, 0.f}};
#pragma unroll
        for (int kk = 0; kk < 8; ++kk) {
#pragma unroll
            for (int t = 0; t < 2; ++t)
                acc[t] = __builtin_amdgcn_mfma_f32_16x16x32_bf16(
                    a[kk], bfrag[t][kk], acc[t], 0, 0, 0);
        }

        // acc = (1/TEMP)*log2(e)*sim ; D: row = wr0+t*16+l15, col = c0+quad*4+j
        const int c0 = c_base + it * 16;
        const bool special = (c0 < wr0 + 32 && c0 + 16 > wr0) ||
                             (c0 < p0 + 32 && c0 + 16 > p0);
        if (!special) {
#pragma unroll
            for (int t = 0; t < 2; ++t) {
                float e0 = fast_exp2(acc[t][0]) + fast_exp2(acc[t][1]);
                float e1 = fast_exp2(acc[t][2]) + fast_exp2(acc[t][3]);
                sum_exp[t] += e0 + e1;
            }
        } else {
#pragma unroll
            for (int t = 0; t < 2; ++t) {
                const int r = wr0 + t * 16 + l15;
#pragma unroll
                for (int j = 0; j < 4; ++j) {
                    const int c = c0 + quad * 4 + j;
                    const float e = fast_exp2(acc[t][j]);
                    sum_exp[t] += (c == r) ? 0.f : e;               // self-diag mask
                    if (c == (r ^ N_HALF)) pos_acc += acc[t][j];    // positive (scaled)
                }
            }
        }
    }

    // Per-row partial: reduce over the 4 quads, one coalesced store per row.
#pragma unroll
    for (int t = 0; t < 2; ++t) {
        float s = sum_exp[t];
        s += __shfl_xor(s, 16, 64);
        s += __shfl_xor(s, 32, 64);
        if (lane < 16)
            rowsum_part[(size_t)cs * TWO_N + wr0 + t * 16 + lane] = s;
    }

    // Positive partial: every wave writes its slot (0 if no partner overlap).
#pragma unroll
    for (int m = 1; m < 64; m <<= 1) pos_acc += __shfl_xor(pos_acc, m, 64);
    if (lane == 0) pos_part[blockIdx.x * 4 + wave] = pos_acc;
}

// ---------------------------------------------------------------------------
// Kernel 3: per-row ln(sum of 16 partials) - ln2 * positive partials, reduced.
// ---------------------------------------------------------------------------
__global__ __launch_bounds__(1024) void fin1_kernel(const float* __restrict__ rowsum_part,
                                                    const float* __restrict__ pos_part,
                                                    float* __restrict__ block_part)
{
    __shared__ float red[16];
    const int t = threadIdx.x;
    const int r = blockIdx.x * 1024 + t;
    float acc = 0.f;
#pragma unroll
    for (int cs = 0; cs < 16; ++cs)
        acc += rowsum_part[(size_t)cs * TWO_N + r];
    float v = logf(acc);
    if (t < 512)
        v -= 0.69314718055994531f * pos_part[blockIdx.x * 512 + t];
#pragma unroll
    for (int m = 1; m < 64; m <<= 1) v += __shfl_xor(v, m, 64);
    if ((t & 63) == 0) red[t >> 6] = v;
    __syncthreads();
    if (t == 0) {
        float s = 0.f;
#pragma unroll
        for (int w = 0; w < 16; ++w) s += red[w];
        block_part[blockIdx.x] = s;
    }
}

__global__ void fin2_kernel(const float* __restrict__ block_part, float* __restrict__ out)
{
    if (threadIdx.x == 0) {
        float s = 0.f;
#pragma unroll
        for (int i = 0; i < 8; ++i) s += block_part[i];
        out[0] = s / (float)TWO_N;
    }
}

// ---------------------------------------------------------------------------
extern "C" void kernel_launch(void* const* d_in, const int* in_sizes, int n_in,
                              void* d_out, int out_size, void* d_ws, size_t ws_size,
                              hipStream_t stream)
{
    const float* zis = (const float*)d_in[0];
    const float* zjs = (const float*)d_in[1];

    // ws: [0,4MB) swizzled bf16; then rowsum partials [16][8192] (512KB);
    //     then pos partials [4096]; then block partials [8].
    unsigned short* swz = (unsigned short*)d_ws;
    float* rowsum_part  = (float*)((char*)d_ws + (size_t)TWO_N * DIMS * sizeof(unsigned short));
    float* pos_part     = rowsum_part + (size_t)16 * TWO_N;
    float* block_part   = pos_part + 4096;

    nrm_kernel<<<TWO_N / 8, 256, 0, stream>>>(zis, zjs, swz);
    ntx_kernel<<<1024, 256, 0, stream>>>((const __bf16*)swz, rowsum_part, pos_part);
    fin1_kernel<<<8, 1024, 0, stream>>>(rowsum_part, pos_part, block_part);
    fin2_kernel<<<1, 64, 0, stream>>>(block_part, (float*)d_out);
}